// Round 1
// baseline (7753.294 us; speedup 1.0000x reference)
//
#include <hip/hip_runtime.h>
#include <hip/hip_bf16.h>
#include <math.h>

#define BB 2
#define TT 1024
#define LL 4
#define HH 12
#define DD 768
#define DHH 64
#define FFF 3072
#define VV 50257
#define MM (BB*TT)   // 2048

// ---------------- embedding + sinusoidal PE ----------------
__global__ void embed_kernel(const int* __restrict__ tokens,
                             const float* __restrict__ emb,
                             float* __restrict__ x) {
    int row = blockIdx.x;            // 0..MM-1 = b*TT + t
    int t = row & (TT - 1);
    int tok = tokens[row];
    for (int d = threadIdx.x; d < DD; d += blockDim.x) {
        int i2 = d & ~1;
        float freq = expf((float)i2 * (-9.210340371976184f / (float)DD));
        float ang = (float)t * freq;
        float pe = (d & 1) ? cosf(ang) : sinf(ang);
        x[(size_t)row * DD + d] = emb[(size_t)tok * DD + d] + pe;
    }
}

// ---------------- layernorm ----------------
__global__ void ln_kernel(const float* __restrict__ x,
                          const float* __restrict__ g,
                          const float* __restrict__ b,
                          float* __restrict__ out) {
    int row = blockIdx.x;
    const float* xr = x + (size_t)row * DD;
    __shared__ float red[256];
    int tid = threadIdx.x;
    float s = 0.f;
    for (int d = tid; d < DD; d += 256) s += xr[d];
    red[tid] = s; __syncthreads();
    for (int w = 128; w > 0; w >>= 1) { if (tid < w) red[tid] += red[tid + w]; __syncthreads(); }
    float mu = red[0] / (float)DD;
    __syncthreads();
    float s2 = 0.f;
    for (int d = tid; d < DD; d += 256) { float t0 = xr[d] - mu; s2 += t0 * t0; }
    red[tid] = s2; __syncthreads();
    for (int w = 128; w > 0; w >>= 1) { if (tid < w) red[tid] += red[tid + w]; __syncthreads(); }
    float rstd = rsqrtf(red[0] / (float)DD + 1e-5f);
    for (int d = tid; d < DD; d += 256)
        out[(size_t)row * DD + d] = (xr[d] - mu) * rstd * g[d] + b[d];
}

// ---------------- rmsnorm ----------------
__global__ void rms_kernel(const float* __restrict__ x,
                           const float* __restrict__ w,
                           float* __restrict__ out) {
    int row = blockIdx.x;
    const float* xr = x + (size_t)row * DD;
    __shared__ float red[256];
    int tid = threadIdx.x;
    float s2 = 0.f;
    for (int d = tid; d < DD; d += 256) { float t0 = xr[d]; s2 += t0 * t0; }
    red[tid] = s2; __syncthreads();
    for (int w2 = 128; w2 > 0; w2 >>= 1) { if (tid < w2) red[tid] += red[tid + w2]; __syncthreads(); }
    float rstd = rsqrtf(red[0] / (float)DD + 1e-6f);
    for (int d = tid; d < DD; d += 256)
        out[(size_t)row * DD + d] = xr[d] * rstd * w[d];
}

// ---------------- generic fp32 tiled GEMM ----------------
// C[m,n] = op(A[M,K] @ B + bias [+ res])
// HEADWISE: B is wq[l]-style [H][K][64]; tile columns (64-wide) align with heads.
template<bool HEADWISE, bool RELU, bool RES>
__global__ void gemm_kernel(const float* __restrict__ A, const float* __restrict__ Bm,
                            const float* __restrict__ bias, const float* __restrict__ res,
                            float* __restrict__ C, int Mdim, int Ndim, int Kdim) {
    __shared__ float As[16][68];   // padded: +4 keeps 16B alignment, kills write conflicts
    __shared__ float Bs[16][64];
    int n0 = blockIdx.x * 64;
    int m0 = blockIdx.y * 64;
    int tid = threadIdx.x;          // 0..255
    const float* Bbase;
    size_t ldb;
    if (HEADWISE) { Bbase = Bm + (size_t)(n0 >> 6) * Kdim * 64; ldb = 64; }
    else          { Bbase = Bm + n0; ldb = (size_t)Ndim; }

    float acc[4][4] = {};
    int tx = tid & 15, ty = tid >> 4;
    int arow  = tid >> 2;           // 0..63
    int acol4 = (tid & 3) * 4;      // 0,4,8,12
    int brow  = tid >> 4;           // 0..15
    int bcol4 = (tid & 15) * 4;     // 0..60
    bool bfull = HEADWISE || (n0 + 64 <= Ndim);

    for (int k0 = 0; k0 < Kdim; k0 += 16) {
        float4 av = *(const float4*)(A + (size_t)(m0 + arow) * Kdim + k0 + acol4);
        As[acol4 + 0][arow] = av.x;
        As[acol4 + 1][arow] = av.y;
        As[acol4 + 2][arow] = av.z;
        As[acol4 + 3][arow] = av.w;
        if (bfull) {
            float4 bv = *(const float4*)(Bbase + (size_t)(k0 + brow) * ldb + bcol4);
            *(float4*)&Bs[brow][bcol4] = bv;
        } else {
            #pragma unroll
            for (int j = 0; j < 4; j++) {
                int n = n0 + bcol4 + j;
                Bs[brow][bcol4 + j] = (n < Ndim) ? Bbase[(size_t)(k0 + brow) * ldb + bcol4 + j] : 0.f;
            }
        }
        __syncthreads();
        #pragma unroll
        for (int kk = 0; kk < 16; kk++) {
            float a4[4], b4[4];
            #pragma unroll
            for (int i = 0; i < 4; i++) a4[i] = As[kk][ty * 4 + i];
            #pragma unroll
            for (int j = 0; j < 4; j++) b4[j] = Bs[kk][tx * 4 + j];
            #pragma unroll
            for (int i = 0; i < 4; i++)
                #pragma unroll
                for (int j = 0; j < 4; j++)
                    acc[i][j] += a4[i] * b4[j];
        }
        __syncthreads();
    }
    #pragma unroll
    for (int i = 0; i < 4; i++) {
        int m = m0 + ty * 4 + i;
        #pragma unroll
        for (int j = 0; j < 4; j++) {
            int n = n0 + tx * 4 + j;
            if (n < Ndim) {
                float vout = acc[i][j] + bias[n];
                if (RES) vout += res[(size_t)m * Ndim + n];
                if (RELU) vout = fmaxf(vout, 0.f);
                C[(size_t)m * Ndim + n] = vout;
            }
        }
    }
}

// ---------------- causal attention, one block per (b,h,t) ----------------
// q,k,v,out: [B*T, H*DH] with col = h*64+e
__global__ void attn_kernel(const float* __restrict__ q, const float* __restrict__ k,
                            const float* __restrict__ v, float* __restrict__ out) {
    int idx = blockIdx.x;
    int t  = idx & (TT - 1);
    int bh = idx >> 10;
    int h = bh % HH, b = bh / HH;
    const size_t base = ((size_t)b * TT) * DD + (size_t)h * DHH;
    __shared__ float qs[DHH];
    __shared__ float sc[TT];
    __shared__ float red[256];
    int tid = threadIdx.x;
    if (tid < DHH) qs[tid] = q[base + (size_t)t * DD + tid];
    __syncthreads();
    const float scale = 0.125f;   // 1/sqrt(64)
    float lmax = -1e30f;
    for (int s = tid; s <= t; s += 256) {
        const float* kr = k + base + (size_t)s * DD;
        float dot = 0.f;
        #pragma unroll
        for (int e = 0; e < DHH; e += 4) {
            float4 kv4 = *(const float4*)(kr + e);
            dot += qs[e] * kv4.x + qs[e + 1] * kv4.y + qs[e + 2] * kv4.z + qs[e + 3] * kv4.w;
        }
        dot *= scale;
        sc[s] = dot;
        lmax = fmaxf(lmax, dot);
    }
    red[tid] = lmax; __syncthreads();
    for (int w = 128; w > 0; w >>= 1) { if (tid < w) red[tid] = fmaxf(red[tid], red[tid + w]); __syncthreads(); }
    float m = red[0];
    __syncthreads();
    float lsum = 0.f;
    for (int s = tid; s <= t; s += 256) { float p = expf(sc[s] - m); sc[s] = p; lsum += p; }
    red[tid] = lsum; __syncthreads();
    for (int w = 128; w > 0; w >>= 1) { if (tid < w) red[tid] += red[tid + w]; __syncthreads(); }
    float inv = 1.f / red[0];
    __syncthreads();
    int e = tid & 63, grp = tid >> 6;
    float acc = 0.f;
    for (int s = grp; s <= t; s += 4) acc += sc[s] * v[base + (size_t)s * DD + e];
    red[tid] = acc; __syncthreads();
    if (tid < 64) {
        float o = (red[tid] + red[tid + 64] + red[tid + 128] + red[tid + 192]) * inv;
        out[base + (size_t)t * DD + e] = o;
    }
}

extern "C" void kernel_launch(void* const* d_in, const int* in_sizes, int n_in,
                              void* d_out, int out_size, void* d_ws, size_t ws_size,
                              hipStream_t stream) {
    const int*   tokens = (const int*)  d_in[0];
    const float* emb    = (const float*)d_in[1];
    const float* wq     = (const float*)d_in[2];
    const float* bq     = (const float*)d_in[3];
    const float* wk     = (const float*)d_in[4];
    const float* bk     = (const float*)d_in[5];
    const float* wv     = (const float*)d_in[6];
    const float* bv     = (const float*)d_in[7];
    const float* wo     = (const float*)d_in[8];
    const float* bo     = (const float*)d_in[9];
    const float* ln1_g  = (const float*)d_in[10];
    const float* ln1_b  = (const float*)d_in[11];
    const float* ln2_g  = (const float*)d_in[12];
    const float* ln2_b  = (const float*)d_in[13];
    const float* w1     = (const float*)d_in[14];
    const float* b1     = (const float*)d_in[15];
    const float* w2     = (const float*)d_in[16];
    const float* b2     = (const float*)d_in[17];
    const float* rms_w  = (const float*)d_in[18];
    const float* wu     = (const float*)d_in[19];
    const float* bu     = (const float*)d_in[20];
    float* out = (float*)d_out;

    const size_t MD = (size_t)MM * DD;
    float* x  = (float*)d_ws;       // [MM, DD]
    float* xn = x  + MD;            // [MM, DD]
    float* qb = xn + MD;            // [MM, DD]
    float* kb = qb + MD;            // [MM, DD]
    float* vb = kb + MD;            // [MM, DD]
    float* ab = vb + MD;            // [MM, DD]
    float* hb = qb;                 // [MM, FFF] aliases qb..ab (4*MD == MM*FFF)

    embed_kernel<<<MM, 256, 0, stream>>>(tokens, emb, x);

    dim3 gD (DD  / 64, MM / 64);
    dim3 gFF(FFF / 64, MM / 64);
    dim3 gV ((VV + 63) / 64, MM / 64);

    for (int l = 0; l < LL; l++) {
        ln_kernel<<<MM, 256, 0, stream>>>(x, ln1_g + l * DD, ln1_b + l * DD, xn);
        const size_t wqkv_off = (size_t)l * HH * DD * DHH;
        gemm_kernel<true , false, false><<<gD, 256, 0, stream>>>(xn, wq + wqkv_off, bq + l * DD, nullptr, qb, MM, DD, DD);
        gemm_kernel<true , false, false><<<gD, 256, 0, stream>>>(xn, wk + wqkv_off, bk + l * DD, nullptr, kb, MM, DD, DD);
        gemm_kernel<true , false, false><<<gD, 256, 0, stream>>>(xn, wv + wqkv_off, bv + l * DD, nullptr, vb, MM, DD, DD);
        attn_kernel<<<BB * HH * TT, 256, 0, stream>>>(qb, kb, vb, ab);
        gemm_kernel<false, false, true ><<<gD, 256, 0, stream>>>(ab, wo + (size_t)l * DD * DD, bo + l * DD, x, x, MM, DD, DD);
        ln_kernel<<<MM, 256, 0, stream>>>(x, ln2_g + l * DD, ln2_b + l * DD, xn);
        gemm_kernel<false, true , false><<<gFF, 256, 0, stream>>>(xn, w1 + (size_t)l * DD * FFF, b1 + l * FFF, nullptr, hb, MM, FFF, DD);
        gemm_kernel<false, false, true ><<<gD, 256, 0, stream>>>(hb, w2 + (size_t)l * FFF * DD, b2 + l * DD, x, x, MM, DD, FFF);
    }

    rms_kernel<<<MM, 256, 0, stream>>>(x, rms_w, xn);
    gemm_kernel<false, false, false><<<gV, 256, 0, stream>>>(xn, wu, bu, nullptr, out, MM, VV, DD);
}

// Round 4
// 3883.010 us; speedup vs baseline: 1.9967x; 1.9967x over previous
//
#include <hip/hip_runtime.h>
#include <math.h>

#define BB 2
#define TT 1024
#define LL 4
#define HH 12
#define DD 768
#define DHH 64
#define FFF 3072
#define VV 50257
#define MM (BB*TT)      // 2048
#define NQKV (3*DD)     // 2304
#define VPAD 50304      // 393*128
#define VCHUNK 8192     // vocab column chunk (64 tiles of 128)

typedef __attribute__((ext_vector_type(8))) short bf16x8;
typedef __attribute__((ext_vector_type(4))) float f32x4;

__device__ __forceinline__ unsigned short f2bf(float x) {
    unsigned int u = __float_as_uint(x);
    u += 0x7FFF + ((u >> 16) & 1);           // round-to-nearest-even
    return (unsigned short)(u >> 16);
}
__device__ __forceinline__ float bf2f(unsigned short u) {
    return __uint_as_float(((unsigned int)u) << 16);
}

// ---------------- embedding + sinusoidal PE (fp32 residual stream) ----------------
__global__ void embed_kernel(const int* __restrict__ tokens,
                             const float* __restrict__ emb,
                             float* __restrict__ x) {
    int row = blockIdx.x;            // b*TT + t
    int t = row & (TT - 1);
    int tok = tokens[row];
    for (int d = threadIdx.x; d < DD; d += blockDim.x) {
        int i2 = d & ~1;
        float freq = expf((float)i2 * (-9.210340371976184f / (float)DD));
        float ang = (float)t * freq;
        float pe = (d & 1) ? cosf(ang) : sinf(ang);
        x[(size_t)row * DD + d] = emb[(size_t)tok * DD + d] + pe;
    }
}

// ---------------- layernorm: fp32 in -> bf16 out ----------------
__global__ void ln_kernel(const float* __restrict__ x,
                          const float* __restrict__ g,
                          const float* __restrict__ b,
                          unsigned short* __restrict__ outB) {
    int row = blockIdx.x;
    const float* xr = x + (size_t)row * DD;
    __shared__ float red[256];
    int tid = threadIdx.x;
    float s = 0.f;
    for (int d = tid; d < DD; d += 256) s += xr[d];
    red[tid] = s; __syncthreads();
    for (int w = 128; w > 0; w >>= 1) { if (tid < w) red[tid] += red[tid + w]; __syncthreads(); }
    float mu = red[0] / (float)DD;
    __syncthreads();
    float s2 = 0.f;
    for (int d = tid; d < DD; d += 256) { float t0 = xr[d] - mu; s2 += t0 * t0; }
    red[tid] = s2; __syncthreads();
    for (int w = 128; w > 0; w >>= 1) { if (tid < w) red[tid] += red[tid + w]; __syncthreads(); }
    float rstd = rsqrtf(red[0] / (float)DD + 1e-5f);
    for (int d = tid; d < DD; d += 256)
        outB[(size_t)row * DD + d] = f2bf((xr[d] - mu) * rstd * g[d] + b[d]);
}

// ---------------- rmsnorm: fp32 in -> bf16 out ----------------
__global__ void rms_kernel(const float* __restrict__ x,
                           const float* __restrict__ w,
                           unsigned short* __restrict__ outB) {
    int row = blockIdx.x;
    const float* xr = x + (size_t)row * DD;
    __shared__ float red[256];
    int tid = threadIdx.x;
    float s2 = 0.f;
    for (int d = tid; d < DD; d += 256) { float t0 = xr[d]; s2 += t0 * t0; }
    red[tid] = s2; __syncthreads();
    for (int w2 = 128; w2 > 0; w2 >>= 1) { if (tid < w2) red[tid] += red[tid + w2]; __syncthreads(); }
    float rstd = rsqrtf(red[0] / (float)DD + 1e-6f);
    for (int d = tid; d < DD; d += 256)
        outB[(size_t)row * DD + d] = f2bf(xr[d] * rstd * w[d]);
}

// ---------------- weight transpose+convert: W[K][ldW] fp32 -> BT[n][k] bf16 ----------------
// BT[n0blk+a][k] = W[k][n_base+n0blk+a], 0 if column >= Nvalid. grid (K/64, Nloc/64)
__global__ void convT(const float* __restrict__ W, unsigned short* __restrict__ BT,
                      int K, int ldW, int n_base, int Nvalid) {
    __shared__ float tile[64][65];
    int k0 = blockIdx.x * 64, n0 = blockIdx.y * 64;
    int tx = threadIdx.x & 63, ty = threadIdx.x >> 6;   // ty 0..3
    #pragma unroll
    for (int i = 0; i < 64; i += 4) {
        int k = k0 + ty + i;
        int n = n_base + n0 + tx;
        tile[ty + i][tx] = (n < Nvalid) ? W[(size_t)k * ldW + n] : 0.f;
    }
    __syncthreads();
    #pragma unroll
    for (int i = 0; i < 64; i += 4) {
        int a = ty + i;
        BT[(size_t)(n0 + a) * K + k0 + tx] = f2bf(tile[tx][a]);
    }
}

// headwise QKV weight: W[H][768][64] -> BT[nrow_base + h*64 + e][k]. grid (768/64, H)
__global__ void convT_head(const float* __restrict__ W, unsigned short* __restrict__ BT,
                           int nrow_base) {
    __shared__ float tile[64][65];
    int k0 = blockIdx.x * 64;
    int h = blockIdx.y;
    const float* Wh = W + (size_t)h * DD * DHH;
    int tx = threadIdx.x & 63, ty = threadIdx.x >> 6;
    #pragma unroll
    for (int i = 0; i < 64; i += 4)
        tile[ty + i][tx] = Wh[(size_t)(k0 + ty + i) * 64 + tx];   // tile[kk][e]
    __syncthreads();
    #pragma unroll
    for (int i = 0; i < 64; i += 4) {
        int e = ty + i;
        BT[(size_t)(nrow_base + h * 64 + e) * DD + k0 + tx] = f2bf(tile[tx][e]);
    }
}

// pack bq|bk|bv into one [2304] bias vector
__global__ void pack_bias(const float* __restrict__ bq, const float* __restrict__ bk,
                          const float* __restrict__ bv, float* __restrict__ o) {
    int i = blockIdx.x * 256 + threadIdx.x;
    if (i < NQKV) {
        float v = (i < DD) ? bq[i] : (i < 2 * DD ? bk[i - DD] : bv[i - 2 * DD]);
        o[i] = v;
    }
}

// ---------------- bf16 MFMA GEMM (128x128 tile, BK=32, 4 waves, reg-staged LDS) ----------------
// A: [M][K] bf16 row-major.  Bt: [Nloc][K] bf16 (pre-transposed).  C col = n_base + local col.
template<bool RELU, bool RES, bool BF16OUT>
__global__ __launch_bounds__(256)
void gemm_bf16(const unsigned short* __restrict__ A,
               const unsigned short* __restrict__ Bt,
               const float* __restrict__ bias,
               const float* __restrict__ res,
               void* __restrict__ Cout,
               int K, int ldc, int n_base, int nlimit) {
    __shared__ __align__(16) unsigned short As[128 * 32];
    __shared__ __align__(16) unsigned short Bs[128 * 32];
    const int tid = threadIdx.x;
    const int m0 = blockIdx.y * 128;
    const int n0 = blockIdx.x * 128;
    const int lane = tid & 63;
    const int wid = tid >> 6;
    const int wr = (wid >> 1) * 64;
    const int wc = (wid & 1) * 64;
    const int fr = lane & 15;       // fragment row/col index
    const int fq = lane >> 4;       // k-group / row-quad
    const int fk = fq * 8;

    // per-thread staging coordinates: granule g = tid + j*256, 16B each
    const int row0 = tid >> 2;            // granule row for j=0 (0..63)
    const int kg   = (tid & 3) * 8;       // k-offset in shorts (0,8,16,24)

    f32x4 acc[4][4] = {};

    for (int k0 = 0; k0 < K; k0 += 32) {
        // load next tiles to registers (no LDS dependency yet)
        int4 va0 = *(const int4*)(A  + (size_t)(m0 + row0)      * K + k0 + kg);
        int4 va1 = *(const int4*)(A  + (size_t)(m0 + row0 + 64) * K + k0 + kg);
        int4 vb0 = *(const int4*)(Bt + (size_t)(n0 + row0)      * K + k0 + kg);
        int4 vb1 = *(const int4*)(Bt + (size_t)(n0 + row0 + 64) * K + k0 + kg);
        __syncthreads();                   // all waves done reading LDS from prev iter
        *(int4*)(As + (size_t)tid * 8)         = va0;
        *(int4*)(As + (size_t)(tid + 256) * 8) = va1;
        *(int4*)(Bs + (size_t)tid * 8)         = vb0;
        *(int4*)(Bs + (size_t)(tid + 256) * 8) = vb1;
        __syncthreads();                   // tiles visible to all waves
        bf16x8 af[4], bfr[4];
        #pragma unroll
        for (int m = 0; m < 4; m++)
            af[m] = *(const bf16x8*)(As + (wr + m * 16 + fr) * 32 + fk);
        #pragma unroll
        for (int n = 0; n < 4; n++)
            bfr[n] = *(const bf16x8*)(Bs + (wc + n * 16 + fr) * 32 + fk);
        #pragma unroll
        for (int m = 0; m < 4; m++)
            #pragma unroll
            for (int n = 0; n < 4; n++)
                acc[m][n] = __builtin_amdgcn_mfma_f32_16x16x32_bf16(af[m], bfr[n], acc[m][n], 0, 0, 0);
    }

    // epilogue: C/D layout col = lane&15, row = (lane>>4)*4 + reg  [m89-verified]
    #pragma unroll
    for (int m = 0; m < 4; m++) {
        #pragma unroll
        for (int n = 0; n < 4; n++) {
            int col = n_base + n0 + wc + n * 16 + fr;
            if (col < nlimit) {
                float bcol = bias[col];
                #pragma unroll
                for (int r2 = 0; r2 < 4; r2++) {
                    int row = m0 + wr + m * 16 + fq * 4 + r2;
                    float v = acc[m][n][r2] + bcol;
                    if (RES) v += res[(size_t)row * ldc + col];
                    if (RELU) v = fmaxf(v, 0.f);
                    if (BF16OUT) ((unsigned short*)Cout)[(size_t)row * ldc + col] = f2bf(v);
                    else         ((float*)Cout)[(size_t)row * ldc + col] = v;
                }
            }
        }
    }
}

// ---------------- causal attention, one block per (b,h,t); fused bf16 qkv buffer ----------------
// qkv: [B*T][2304] bf16 (q | k | v each 768 wide).  out: bf16 [B*T][768]
__global__ void attn_kernel(const unsigned short* __restrict__ qkv,
                            unsigned short* __restrict__ outB) {
    int idx = blockIdx.x;
    int t  = idx & (TT - 1);
    int bh = idx >> 10;
    int h = bh % HH, b = bh / HH;
    const size_t rowb = (size_t)b * TT;
    const unsigned short* qrow = qkv + (rowb + t) * NQKV + h * DHH;
    __shared__ float qs[DHH];
    __shared__ float sc[TT];
    __shared__ float red[256];
    int tid = threadIdx.x;
    if (tid < DHH) qs[tid] = bf2f(qrow[tid]);
    __syncthreads();
    const float scale = 0.125f;   // 1/sqrt(64)
    float lmax = -1e30f;
    for (int s = tid; s <= t; s += 256) {
        const unsigned short* kr = qkv + (rowb + s) * NQKV + DD + h * DHH;
        float dot = 0.f;
        #pragma unroll
        for (int e = 0; e < DHH; e += 8) {
            bf16x8 kv = *(const bf16x8*)(kr + e);
            #pragma unroll
            for (int j = 0; j < 8; j++)
                dot += qs[e + j] * bf2f((unsigned short)kv[j]);
        }
        dot *= scale;
        sc[s] = dot;
        lmax = fmaxf(lmax, dot);
    }
    red[tid] = lmax; __syncthreads();
    for (int w = 128; w > 0; w >>= 1) { if (tid < w) red[tid] = fmaxf(red[tid], red[tid + w]); __syncthreads(); }
    float m = red[0];
    __syncthreads();
    float lsum = 0.f;
    for (int s = tid; s <= t; s += 256) { float p = expf(sc[s] - m); sc[s] = p; lsum += p; }
    red[tid] = lsum; __syncthreads();
    for (int w = 128; w > 0; w >>= 1) { if (tid < w) red[tid] += red[tid + w]; __syncthreads(); }
    float inv = 1.f / red[0];
    __syncthreads();
    int e = tid & 63, grp = tid >> 6;
    float acc = 0.f;
    for (int s = grp; s <= t; s += 4)
        acc += sc[s] * bf2f(qkv[(rowb + s) * NQKV + 2 * DD + h * DHH + e]);
    red[tid] = acc; __syncthreads();
    if (tid < 64) {
        float o = (red[tid] + red[tid + 64] + red[tid + 128] + red[tid + 192]) * inv;
        outB[(rowb + t) * DD + h * DHH + e] = f2bf(o);
    }
}

extern "C" void kernel_launch(void* const* d_in, const int* in_sizes, int n_in,
                              void* d_out, int out_size, void* d_ws, size_t ws_size,
                              hipStream_t stream) {
    const int*   tokens = (const int*)  d_in[0];
    const float* emb    = (const float*)d_in[1];
    const float* wq     = (const float*)d_in[2];
    const float* bq     = (const float*)d_in[3];
    const float* wk     = (const float*)d_in[4];
    const float* bk     = (const float*)d_in[5];
    const float* wv     = (const float*)d_in[6];
    const float* bv     = (const float*)d_in[7];
    const float* wo     = (const float*)d_in[8];
    const float* bo     = (const float*)d_in[9];
    const float* ln1_g  = (const float*)d_in[10];
    const float* ln1_b  = (const float*)d_in[11];
    const float* ln2_g  = (const float*)d_in[12];
    const float* ln2_b  = (const float*)d_in[13];
    const float* w1     = (const float*)d_in[14];
    const float* b1     = (const float*)d_in[15];
    const float* w2     = (const float*)d_in[16];
    const float* b2     = (const float*)d_in[17];
    const float* rms_w  = (const float*)d_in[18];
    const float* wu     = (const float*)d_in[19];
    const float* bu     = (const float*)d_in[20];
    float* out = (float*)d_out;

    const size_t MD = (size_t)MM * DD;
    // workspace layout — 33.0 MiB total (baseline proved >= 36 MiB available)
    float* x             = (float*)d_ws;                                // [MM][DD] fp32      6.29 MB
    unsigned short* xnB  = (unsigned short*)(x + MD);                   // [MM][DD] bf16      3.15 MB
    unsigned short* qkvB = xnB + MD;                                    // [MM][2304] bf16    9.44 MB
    unsigned short* abB  = qkvB + (size_t)MM * NQKV;                    // [MM][DD] bf16      3.15 MB
    unsigned short* wT   = abB + MD;                                    // [VCHUNK][768] bf16 12.58 MB (reused)
    float* bqkv          = (float*)(wT + (size_t)VCHUNK * DD);          // [2304]             9 KB
    unsigned short* hbB  = qkvB;  // [MM][FFF] bf16 aliases qkvB+abB (4.72M+1.57M = 6.29M shorts exactly)

    embed_kernel<<<MM, 256, 0, stream>>>(tokens, emb, x);

    for (int l = 0; l < LL; l++) {
        const size_t wqkv_off = (size_t)l * HH * DD * DHH;
        ln_kernel<<<MM, 256, 0, stream>>>(x, ln1_g + l * DD, ln1_b + l * DD, xnB);
        convT_head<<<dim3(DD / 64, HH), 256, 0, stream>>>(wq + wqkv_off, wT, 0);
        convT_head<<<dim3(DD / 64, HH), 256, 0, stream>>>(wk + wqkv_off, wT, DD);
        convT_head<<<dim3(DD / 64, HH), 256, 0, stream>>>(wv + wqkv_off, wT, 2 * DD);
        pack_bias<<<9, 256, 0, stream>>>(bq + l * DD, bk + l * DD, bv + l * DD, bqkv);
        gemm_bf16<false, false, true><<<dim3(NQKV / 128, MM / 128), 256, 0, stream>>>(
            xnB, wT, bqkv, nullptr, qkvB, DD, NQKV, 0, NQKV);
        attn_kernel<<<BB * HH * TT, 256, 0, stream>>>(qkvB, abB);
        convT<<<dim3(DD / 64, DD / 64), 256, 0, stream>>>(wo + (size_t)l * DD * DD, wT, DD, DD, 0, DD);
        gemm_bf16<false, true, false><<<dim3(DD / 128, MM / 128), 256, 0, stream>>>(
            abB, wT, bo + l * DD, x, x, DD, DD, 0, DD);
        ln_kernel<<<MM, 256, 0, stream>>>(x, ln2_g + l * DD, ln2_b + l * DD, xnB);
        convT<<<dim3(DD / 64, FFF / 64), 256, 0, stream>>>(w1 + (size_t)l * DD * FFF, wT, DD, FFF, 0, FFF);
        gemm_bf16<true, false, true><<<dim3(FFF / 128, MM / 128), 256, 0, stream>>>(
            xnB, wT, b1 + l * FFF, nullptr, hbB, DD, FFF, 0, FFF);
        convT<<<dim3(FFF / 64, DD / 64), 256, 0, stream>>>(w2 + (size_t)l * FFF * DD, wT, FFF, DD, 0, DD);
        gemm_bf16<false, true, false><<<dim3(DD / 128, MM / 128), 256, 0, stream>>>(
            hbB, wT, b2 + l * DD, x, x, FFF, DD, 0, DD);
    }

    rms_kernel<<<MM, 256, 0, stream>>>(x, rms_w, xnB);
    for (int n0 = 0; n0 < VPAD; n0 += VCHUNK) {
        int nc = (VPAD - n0 < VCHUNK) ? (VPAD - n0) : VCHUNK;
        convT<<<dim3(DD / 64, nc / 64), 256, 0, stream>>>(wu, wT, DD, VV, n0, VV);
        gemm_bf16<false, false, false><<<dim3(nc / 128, MM / 128), 256, 0, stream>>>(
            xnB, wT, bu, nullptr, out, DD, VV, n0, VV);
    }
}